// Round 1
// 98.514 us; speedup vs baseline: 1.0246x; 1.0246x over previous
//
#include <hip/hip_runtime.h>
#include <math.h>

#define NB 128
#define NM 32
#define NN 64
#define NK 2048
#define NP (NN + NK - 1)   // 2111 float2 positions
#define NQ 4               // blocks per batch
#define QSZ 528            // positions per block (4*528 = 2112 >= 2111)
#define WSPAN 592          // staged reversed-W window (float2 entries)

typedef float v2f __attribute__((ext_vector_type(2)));

__device__ __forceinline__ float fast_sigmoid(float x) {
    // rcp(1+exp(-x)): v_exp_f32 + v_rcp_f32, ~1e-7 rel err << 4e-3 budget
    return __builtin_amdgcn_rcpf(1.f + __expf(-x));
}
__device__ __forceinline__ float fast_tanh(float x) {
    // 1 - 2/(1+exp(2x)); exact at +-inf, monotone, ~1e-7 rel err
    return 1.f - 2.f * __builtin_amdgcn_rcpf(1.f + __expf(2.f * x));
}

__global__ __launch_bounds__(256) void gen_cell_kernel(
    const float* __restrict__ qt1,
    const float* __restrict__ ht1,
    const float* __restrict__ zt,
    const float* __restrict__ alpha_t,
    const float* __restrict__ conv_w,
    const float* __restrict__ conv_b,
    const float* __restrict__ W_xr, const float* __restrict__ W_hr, const float* __restrict__ b_r,
    const float* __restrict__ W_xu, const float* __restrict__ W_hu, const float* __restrict__ b_u,
    const float* __restrict__ W_xn, const float* __restrict__ W_hn, const float* __restrict__ b_n,
    const float* __restrict__ lin_w, const float* __restrict__ lin_b,
    const float* __restrict__ W_emb,
    float* __restrict__ out)
{
    const int b   = blockIdx.x >> 2;
    const int q   = blockIdx.x & 3;
    const int tid = threadIdx.x;
    const int plo = q * QSZ;

    __shared__ __align__(16) float2 s_wr[WSPAN];  // reversed W window, ~4.7 KB
    __shared__ __align__(16) float s_ht[2 * NN];
    __shared__ float s_s[NN];

    const float2* q2 = (const float2*)qt1 + (size_t)b * 2048;

    // ---- Early prefetch of all q-shift/st inputs: issued before any LDS/compute
    // so the HBM/L2 latency hides under stages 1-3.
    const int p0 = plo + tid;          // always < 2048 (max 1839)
    const int p1 = p0 + 256;           // max 2095, may be >= 2048
    float2 qv0 = q2[p0];
    float2 qv1; qv1.x = 0.f; qv1.y = 0.f;
    if (p1 < 2048) qv1 = q2[p1];
    // tail prefetch (wave 1 handles tail positions plo+512 .. plo+527)
    float2 qv2; qv2.x = 0.f; qv2.y = 0.f;
    if (tid >= 64 && tid < 128) {
        const int pt = plo + 512 + ((tid - 64) >> 2);
        if (pt < 2048) qv2 = q2[pt];
    }

    // Stage reversed+padded W window: R_global[i] = (64<=i<2112) ? w2[NP-i] : 0,
    // local window j in [0,591) maps to i = (1584 - plo) + j.
    {
        const float2* w2g = (const float2*)W_emb;
        const int i_min = 1584 - plo;
        float2 z2; z2.x = 0.f; z2.y = 0.f;
        for (int j = tid; j < 591; j += 256) {
            int i = i_min + j;
            float2 v = (i >= 64 && i < 2112) ? w2g[NP - i] : z2;
            s_wr[j] = v;
        }
    }

    float2* st2 = (float2*)out;                              // [B,64]
    float2* qt2 = (float2*)out + NB * NN;                    // [B,2048]
    float*  ht_out = out + NB * NN * 2 + NB * NM * NN * 2;   // [B,N,2]

    // ---- Stage 1: Ht1 conv + GRU gates (threads 0..63, one per n) ----
    if (tid < NN) {
        const int n = tid;
        const float* qp = qt1 + (size_t)b * (NM * NN * 2) + n * 2;
        // 2-way split accumulator chains (even/odd rows) to halve dep-chain length
        float h0a = 0.f, h0b = 0.f, h1a = 0.f, h1b = 0.f;
        #pragma unroll
        for (int h = 0; h < NM; h += 2) {
            float m0 = qp[h * (NN * 2)];
            float m1 = qp[h * (NN * 2) + 1];
            float m2 = qp[(h + 1) * (NN * 2)];
            float m3 = qp[(h + 1) * (NN * 2) + 1];
            h0a = fmaf(m0, conv_w[h],       fmaf(m1, conv_w[33 + h],  h0a));
            h0b = fmaf(m2, conv_w[h + 1],   fmaf(m3, conv_w[34 + h],  h0b));
            h1a = fmaf(m0, conv_w[66 + h],  fmaf(m1, conv_w[99 + h],  h1a));
            h1b = fmaf(m2, conv_w[67 + h],  fmaf(m3, conv_w[100 + h], h1b));
        }
        const float hp0 = ht1[b * (NN * 2) + n * 2];
        const float hp1 = ht1[b * (NN * 2) + n * 2 + 1];
        float h0 = h0a + h0b + conv_b[0];
        float h1 = h1a + h1b + conv_b[1];
        h0 = fmaf(hp0, conv_w[32], fmaf(hp1, conv_w[65],  h0));
        h1 = fmaf(hp0, conv_w[98], fmaf(hp1, conv_w[131], h1));

        const float x0 = zt[b * NN + n];
        const float x1 = alpha_t[b * NN + n];

        float pr0 = x0*W_xr[0] + x1*W_xr[2] + h0*W_hr[0] + h1*W_hr[2] + b_r[0];
        float pr1 = x0*W_xr[1] + x1*W_xr[3] + h0*W_hr[1] + h1*W_hr[3] + b_r[1];
        float r0 = fast_sigmoid(pr0);
        float r1 = fast_sigmoid(pr1);

        float pu0 = x0*W_xu[0] + x1*W_xu[2] + h0*W_hu[0] + h1*W_hu[2] + b_u[0];
        float pu1 = x0*W_xu[1] + x1*W_xu[3] + h0*W_hu[1] + h1*W_hu[3] + b_u[1];
        float u0 = fast_sigmoid(pu0);
        float u1 = fast_sigmoid(pu1);

        float g0 = r0 * h0, g1 = r1 * h1;
        float pn0 = x0*W_xn[0] + x1*W_xn[2] + g0*W_hn[0] + g1*W_hn[2] + b_n[0];
        float pn1 = x0*W_xn[1] + x1*W_xn[3] + g0*W_hn[1] + g1*W_hn[3] + b_n[1];
        float nt0 = fast_tanh(pn0);
        float nt1 = fast_tanh(pn1);

        float ho0 = u0 * hp0 + (1.f - u0) * nt0;
        float ho1 = u1 * hp1 + (1.f - u1) * nt1;
        s_ht[n * 2]     = ho0;
        s_ht[n * 2 + 1] = ho1;
        if (q == 0) {
            ht_out[b * (NN * 2) + n * 2]     = ho0;
            ht_out[b * (NN * 2) + n * 2 + 1] = ho1;
        }
    }
    __syncthreads();

    // ---- Stage 2: it = ht_flat @ lin_w[n] + lin_b; s = it * alpha ----
    // All 256 threads: 4 lanes per n, interleaved j = sub + 4*jj (bank-conflict free),
    // shfl-xor reduce within the 4-lane group.
    {
        const int n   = tid >> 2;
        const int sub = tid & 3;
        const float4* lw4 = (const float4*)(lin_w + n * (2 * NN));
        const float4* h4  = (const float4*)s_ht;
        float acc = 0.f;
        #pragma unroll
        for (int jj = 0; jj < 8; ++jj) {
            const int j = sub + 4 * jj;
            float4 lw = lw4[j];
            float4 hv = h4[j];
            acc = fmaf(lw.x, hv.x, acc);
            acc = fmaf(lw.y, hv.y, acc);
            acc = fmaf(lw.z, hv.z, acc);
            acc = fmaf(lw.w, hv.w, acc);
        }
        acc += __shfl_xor(acc, 1);
        acc += __shfl_xor(acc, 2);
        if (sub == 0) s_s[n] = (acc + lin_b[n]) * alpha_t[b * NN + n];
    }
    __syncthreads();

    // each lane caches s[lane]; loop broadcasts via readlane (scalar-operand FMA)
    const float s_reg = s_s[tid & 63];

    // ---- Stage 3: FIR + fused direct store ----
    // f2[p] = sum_n s[n] * w2[p-n] = sum_n s[n] * R_local[(527 - (p-plo)) + n]
    {
        const float2* R0 = s_wr + (527 - tid);   // p0 = plo + tid
        const float2* R1 = R0 - 256;             // p1 = plo + 256 + tid
        v2f a0 = {0.f, 0.f};
        v2f a1 = {0.f, 0.f};
        #pragma unroll 16
        for (int n = 0; n < NN; ++n) {
            float sv = __uint_as_float(
                __builtin_amdgcn_readlane(__float_as_uint(s_reg), n));
            v2f w0 = *(const v2f*)(R0 + n);
            v2f w1 = *(const v2f*)(R1 + n);
            a0 += w0 * sv;   // packed fp32 fma (v_pk_fma_f32)
            a1 += w1 * sv;
        }
        // position p0 = plo + tid (< 2048 always; st gets q2 add too)
        {
            float2 res; res.x = a0.x + qv0.x; res.y = a0.y + qv0.y;
            if (p0 < 64) st2[b * 64 + p0] = res;
            else         qt2[(size_t)b * 2048 + p0 - 64] = res;
        }
        // position p1 = plo + 256 + tid  (always >= 256 > 64; qv1 zero if p1>=2048)
        {
            float2 res; res.x = a1.x + qv1.x; res.y = a1.y + qv1.y;
            qt2[(size_t)b * 2048 + p1 - 64] = res;
        }
    }

    // ---- Tail: positions plo+512 .. plo+527, on wave 1 (wave 0 carries stage 1).
    // 4 lanes per position, 16 terms each, shfl-xor reduce.
    if (tid >= 64 && tid < 128) {
        const int l   = tid - 64;
        const int i   = l >> 2;
        const int sub = l & 3;
        const int p   = plo + 512 + i;
        const float2* Rt = s_wr + (15 - i + sub);
        v2f acc = {0.f, 0.f};
        #pragma unroll
        for (int j = 0; j < 16; ++j) {
            float sv = s_s[sub + 4 * j];      // 4 distinct addrs -> broadcast, no conflict
            v2f wv = *(const v2f*)(Rt + 4 * j);
            acc += wv * sv;
        }
        acc.x += __shfl_xor(acc.x, 1);
        acc.y += __shfl_xor(acc.y, 1);
        acc.x += __shfl_xor(acc.x, 2);
        acc.y += __shfl_xor(acc.y, 2);
        if (sub == 0 && p < NP) {
            float2 res; res.x = acc.x + qv2.x; res.y = acc.y + qv2.y;
            qt2[(size_t)b * 2048 + p - 64] = res;
        }
    }

    // qt2[b][2047] has no f contribution (p=2111 doesn't exist) and no q_shift
    // (y>=1984) -> zero. One writer: block q==3, tid==0.
    if (q == 3 && tid == 0) {
        float2 z; z.x = 0.f; z.y = 0.f;
        qt2[(size_t)b * 2048 + 2047] = z;
    }
}

extern "C" void kernel_launch(void* const* d_in, const int* in_sizes, int n_in,
                              void* d_out, int out_size, void* d_ws, size_t ws_size,
                              hipStream_t stream) {
    (void)in_sizes; (void)n_in; (void)out_size; (void)d_ws; (void)ws_size;
    gen_cell_kernel<<<dim3(NB * NQ), dim3(256), 0, stream>>>(
        (const float*)d_in[0],  (const float*)d_in[1],  (const float*)d_in[2],
        (const float*)d_in[3],  (const float*)d_in[4],  (const float*)d_in[5],
        (const float*)d_in[6],  (const float*)d_in[7],  (const float*)d_in[8],
        (const float*)d_in[9],  (const float*)d_in[10], (const float*)d_in[11],
        (const float*)d_in[12], (const float*)d_in[13], (const float*)d_in[14],
        (const float*)d_in[15], (const float*)d_in[16], (const float*)d_in[17],
        (float*)d_out);
}